// Round 8
// baseline (674.018 us; speedup 1.0000x reference)
//
#include <hip/hip_runtime.h>
#include <cstdint>
#include <cstddef>

#define B_ 2048
#define N_ 62
#define FIN_ 128
#define HID_ 512
#define HEADS_ 8
#define FOUT_ 64
#define LAYERS_ 3
#define M_ (B_*N_)

typedef __bf16 bf16x8 __attribute__((ext_vector_type(8)));
typedef __bf16 bf16x4 __attribute__((ext_vector_type(4)));
typedef float  f32x4  __attribute__((ext_vector_type(4)));
typedef unsigned short u16;

#define LOG2E 1.4426950408889634f

#if __has_builtin(__builtin_amdgcn_exp2f)
#define EXP2F(x) __builtin_amdgcn_exp2f(x)
#else
#define EXP2F(x) exp2f(x)
#endif
#if __has_builtin(__builtin_amdgcn_logf)
#define LOG2F(x) __builtin_amdgcn_logf(x)
#else
#define LOG2F(x) log2f(x)
#endif

static __device__ __forceinline__ u16 f2bf(float f) {
    union { float f; uint32_t u; } v; v.f = f;
    uint32_t u = v.u;
    return (u16)((u + 0x7fffu + ((u >> 16) & 1u)) >> 16);
}
static __device__ __forceinline__ float bf2f(u16 s) {
    union { uint32_t u; float f; } v; v.u = ((uint32_t)s) << 16;
    return v.f;
}
static __device__ __forceinline__ float rdlane(float v, int l) {
    union { float f; int i; } a, b; a.f = v;
    b.i = __builtin_amdgcn_readlane(a.i, l);
    return b.f;
}
// compiler-friendly pack: emits v_cvt_pk_bf16_f32 pairs (RNE)
static __device__ __forceinline__ bf16x4 pack4(f32x4 v) {
    bf16x4 o;
    o[0] = (__bf16)v[0]; o[1] = (__bf16)v[1];
    o[2] = (__bf16)v[2]; o[3] = (__bf16)v[3];
    return o;
}

// ---------------------------------------------------------------------------
// Pack weights:
//  wmlp_t[n][k]  (n = feature 0..511, k = 0..127), bf16
//  wgat2[l][h][64][512]: row d = W_head^T (col k).
// ---------------------------------------------------------------------------
__global__ __launch_bounds__(256) void repack_w(
    const float* __restrict__ Wm, const float* __restrict__ Wg,
    u16* __restrict__ wmlp_t, u16* __restrict__ wgat2)
{
    int idx = blockIdx.x * 256 + threadIdx.x;
    const int T1 = HID_ * FIN_;                    // 65536
    const int T2 = LAYERS_ * HEADS_ * 64 * HID_;   // 786432
    if (idx < T1) {
        int n = idx / FIN_, k = idx % FIN_;
        wmlp_t[idx] = f2bf(Wm[k * HID_ + n]);
    } else if (idx < T1 + T2) {
        int j = idx - T1;
        int lh = j / (64 * HID_);
        int r  = j % (64 * HID_);
        int n = r / HID_, k = r % HID_;
        wgat2[j] = f2bf(Wg[((size_t)lh * HID_ + k) * FOUT_ + n]);
    }
}

// ---------------------------------------------------------------------------
// adjacency -> per-row 64-bit masks + transposed (per-column) masks
// ---------------------------------------------------------------------------
__global__ __launch_bounds__(256) void build_masks(
    const int* __restrict__ adj, uint64_t* __restrict__ masks,
    uint64_t* __restrict__ masksT)
{
    __shared__ uint32_t m32[128];
    const int b = blockIdx.x, tid = threadIdx.x;
    if (tid < 128) m32[tid] = 0;
    __syncthreads();
    const int* a = adj + (size_t)b * N_ * N_;
    for (int idx = tid; idx < N_ * N_; idx += 256) {
        int i = idx / N_, j = idx % N_;
        if (a[idx] > 0) atomicOr(&m32[i * 2 + (j >> 5)], 1u << (j & 31));
    }
    __syncthreads();
    if (tid < 128) ((uint32_t*)(masks + (size_t)b * 64))[tid] = m32[tid];
    if (tid < 64) {
        int j = tid;
        uint64_t c = 0;
        for (int i = 0; i < N_; i++) {
            uint64_t bit = (m32[i * 2 + (j >> 5)] >> (j & 31)) & 1u;
            c |= bit << i;
        }
        masksT[(size_t)b * 64 + j] = c;
    }
}

// ---------------------------------------------------------------------------
// Fully fused network, one block per graph, wave = head.
// Register budget: __launch_bounds__(512,4) => 128 unified/wave (64 AGPR acc
// + <64 arch). Weight loads use depth-1 prefetch (window fits; r6's depth-4
// spilled). Softmax factorized (exact):
//   exp2(leaky(f2_i+f1_j) - LS_j) = max(A_i*BN_j, C_i*DN_j),
//   A=exp2(f2-pm)<=1, C=exp2(.2(f2-pm))<=1, BN=exp2(pm+f1-LS)<=1,
//   DN=exp2(.2(pm+f1)-LS)<=1  -> no overflow, no exp2 in inner loops.
// Phase order: proj(prefetch) -> f1/f2 butterfly -> stats(BN/DN) -> bar(A)
//   -> hT store (acc dies) -> PV -> ELU -> bar(C)
// ---------------------------------------------------------------------------
#define S_R  72      // u16 stride inside a region
#define RSZ  4608    // u16 size of a region (64*72)
#define S_X  136     // u16 stride for x-stage [64][S_X]
#define X0   27648   // u16 offset of x-stage (regions 6,7)

__global__ __launch_bounds__(512, 4) void gat_fused(
    const float* __restrict__ x,
    const float* __restrict__ bng, const float* __restrict__ bnb,
    const float* __restrict__ bnm, const float* __restrict__ bnv,
    const u16* __restrict__ wmlp_t, const float* __restrict__ bm,
    const u16* __restrict__ wgat2, const float* __restrict__ ag,
    const uint64_t* __restrict__ masks, const uint64_t* __restrict__ masksT,
    const float* __restrict__ Wout, const float* __restrict__ bout,
    float* __restrict__ out)
{
    __shared__ __align__(16) u16 buf[36864];
    __shared__ uint64_t msk[64];
    __shared__ __align__(16) float fstat[1544];
    float* F1 = fstat;          // [8][64] f1, then BN after stats
    float* F2 = fstat + 512;    // [8][64] f2 (raw, kept)
    float* LS = fstat + 1024;   // [8][64] DN after stats

    const int tid = threadIdx.x, b = blockIdx.x;
    const int wave = tid >> 6, lane = tid & 63;
    const int lr = lane & 15, lq = lane >> 4;
    const int w64 = wave * 64;
    const int wreg = wave * RSZ;

    // per-lane transposed column mask (bit i = adj[i][lane])
    const uint64_t cm = masksT[(size_t)b * 64 + lane];
    const uint32_t cml = (uint32_t)cm, cmh = (uint32_t)(cm >> 32);

    // ---- stage BN(x) -> xs bf16 [64][136] (rows 62,63 zero); stage msk ----
    {
        const float* xg = x + (size_t)b * N_ * FIN_;
        for (int idx = tid; idx < 2048; idx += 512) {
            int n = idx >> 5, kq = idx & 31;
            bf16x4 o = {(__bf16)0.f, (__bf16)0.f, (__bf16)0.f, (__bf16)0.f};
            if (n < N_) {
                float s = bng[n] * rsqrtf(bnv[n] + 1e-5f);
                float sh = bnb[n] - bnm[n] * s;
                float4 v = *(const float4*)(xg + n * FIN_ + kq * 4);
                o[0] = (__bf16)(v.x * s + sh); o[1] = (__bf16)(v.y * s + sh);
                o[2] = (__bf16)(v.z * s + sh); o[3] = (__bf16)(v.w * s + sh);
            }
            *(bf16x4*)&buf[X0 + n * S_X + kq * 4] = o;
        }
        if (tid < 64) msk[tid] = (tid < N_) ? masks[(size_t)b * 64 + tid] : 0ull;
    }
    __syncthreads();

    // ---- MLP (operand-swapped): C[feature][node]; feature block w -> region w
    {
        f32x4 acc[4][4];
#pragma unroll
        for (int mt = 0; mt < 4; mt++)
#pragma unroll
            for (int nt = 0; nt < 4; nt++) acc[mt][nt] = (f32x4){0.f, 0.f, 0.f, 0.f};
        const int c0 = w64;
        const u16* wml = wmlp_t + (size_t)(c0 + lr) * FIN_ + lq * 8;
        bf16x8 wcur[4];
#pragma unroll
        for (int mt = 0; mt < 4; mt++)
            wcur[mt] = *(const bf16x8*)(wml + mt * 16 * FIN_);
#pragma unroll 1
        for (int kt = 0; kt < 4; kt++) {
            bf16x8 wnxt[4];
            if (kt < 3) {
#pragma unroll
                for (int mt = 0; mt < 4; mt++)
                    wnxt[mt] = *(const bf16x8*)(wml + mt * 16 * FIN_ + (kt + 1) * 32);
            }
            int k0 = kt * 32;
            bf16x8 xf[4];
#pragma unroll
            for (int nt = 0; nt < 4; nt++)
                xf[nt] = *(const bf16x8*)&buf[X0 + (nt * 16 + lr) * S_X + k0 + lq * 8];
#pragma unroll
            for (int mt = 0; mt < 4; mt++)
#pragma unroll
                for (int nt = 0; nt < 4; nt++)
                    acc[mt][nt] = __builtin_amdgcn_mfma_f32_16x16x32_bf16(
                        wcur[mt], xf[nt], acc[mt][nt], 0, 0, 0);
            if (kt < 3) {
#pragma unroll
                for (int mt = 0; mt < 4; mt++) wcur[mt] = wnxt[mt];
            }
        }
        __syncthreads();   // xs reads done before region writes (waves 6,7 alias xs)
        f32x4 bl[4];
#pragma unroll
        for (int mt = 0; mt < 4; mt++)
            bl[mt] = *(const f32x4*)&bm[c0 + mt * 16 + lq * 4];
#pragma unroll
        for (int mt = 0; mt < 4; mt++)
#pragma unroll
            for (int nt = 0; nt < 4; nt++) {
                int node = nt * 16 + lr;
                *(bf16x4*)&buf[wreg + node * S_R + mt * 16 + lq * 4] =
                    pack4(acc[mt][nt] + bl[mt]);
            }
        // zero pad rows 62,63 of own region (after, same-wave order)
        if (lane < 16) {
            uint4 z = {0u, 0u, 0u, 0u};
            *(uint4*)&buf[wreg + (N_ + (lane >> 3)) * S_R + (lane & 7) * 8] = z;
        }
    }
    __syncthreads();

    // ---- GAT layers ----
#pragma unroll 1
    for (int l = 0; l < LAYERS_; l++) {
        const u16* wp = wgat2 + (size_t)(l * HEADS_ + wave) * 64 * HID_;
        const u16* wpl = wp + (size_t)lr * HID_ + lq * 8;

        // ---- main projection: h = hin @ W_head, depth-1 weight prefetch ----
        // acc[mt][nt][r] = h[node = mt*16+lq*4+r][d = nt*16+lr]
        f32x4 acc[4][4];
#pragma unroll
        for (int mt = 0; mt < 4; mt++)
#pragma unroll
            for (int nt = 0; nt < 4; nt++) acc[mt][nt] = (f32x4){0.f, 0.f, 0.f, 0.f};
        bf16x8 bcur[4];
#pragma unroll
        for (int nt = 0; nt < 4; nt++)
            bcur[nt] = *(const bf16x8*)(wpl + nt * 16 * HID_);
#pragma unroll 1
        for (int kt = 0; kt < 16; kt++) {
            bf16x8 bnxt[4];
            if (kt < 15) {
#pragma unroll
                for (int nt = 0; nt < 4; nt++)
                    bnxt[nt] = *(const bf16x8*)(wpl + nt * 16 * HID_ + (kt + 1) * 32);
            }
            int koff = (kt >> 1) * RSZ + (kt & 1) * 32 + lq * 8;
            bf16x8 af[4];
#pragma unroll
            for (int mt = 0; mt < 4; mt++)
                af[mt] = *(const bf16x8*)&buf[koff + (mt * 16 + lr) * S_R];
#pragma unroll
            for (int nt = 0; nt < 4; nt++)
#pragma unroll
                for (int mt = 0; mt < 4; mt++)
                    acc[mt][nt] = __builtin_amdgcn_mfma_f32_16x16x32_bf16(
                        af[mt], bcur[nt], acc[mt][nt], 0, 0, 0);
            if (kt < 15) {
#pragma unroll
                for (int nt = 0; nt < 4; nt++) bcur[nt] = bnxt[nt];
            }
        }

        // ---- f1/f2 in-register from acc (lr-group butterfly) ----
        {
            float a1v[4], a2v[4];
            const float* agl = ag + (size_t)(l * HEADS_ + wave) * 128;
#pragma unroll
            for (int nt = 0; nt < 4; nt++) {
                a1v[nt] = agl[nt * 16 + lr] * LOG2E;
                a2v[nt] = agl[64 + nt * 16 + lr] * LOG2E;
            }
            float p1v[16], p2v[16];
#pragma unroll
            for (int mt = 0; mt < 4; mt++)
#pragma unroll
                for (int r = 0; r < 4; r++) {
                    float s1 = 0.f, s2 = 0.f;
#pragma unroll
                    for (int nt = 0; nt < 4; nt++) {
                        float hv = acc[mt][nt][r];
                        s1 = fmaf(hv, a1v[nt], s1);
                        s2 = fmaf(hv, a2v[nt], s2);
                    }
                    p1v[mt * 4 + r] = s1;
                    p2v[mt * 4 + r] = s2;
                }
#pragma unroll
            for (int c = 0; c < 8; c++) {
                float tA = __shfl_xor(p1v[c], 8, 64);
                float tB = __shfl_xor(p1v[c + 8], 8, 64);
                p1v[c] = (lr & 8) ? (p1v[c + 8] + tB) : (p1v[c] + tA);
                float uA = __shfl_xor(p2v[c], 8, 64);
                float uB = __shfl_xor(p2v[c + 8], 8, 64);
                p2v[c] = (lr & 8) ? (p2v[c + 8] + uB) : (p2v[c] + uA);
            }
#pragma unroll
            for (int c = 0; c < 4; c++) {
                float tA = __shfl_xor(p1v[c], 4, 64);
                float tB = __shfl_xor(p1v[c + 4], 4, 64);
                p1v[c] = (lr & 4) ? (p1v[c + 4] + tB) : (p1v[c] + tA);
                float uA = __shfl_xor(p2v[c], 4, 64);
                float uB = __shfl_xor(p2v[c + 4], 4, 64);
                p2v[c] = (lr & 4) ? (p2v[c + 4] + uB) : (p2v[c] + uA);
            }
#pragma unroll
            for (int c = 0; c < 2; c++) {
                float tA = __shfl_xor(p1v[c], 2, 64);
                float tB = __shfl_xor(p1v[c + 2], 2, 64);
                p1v[c] = (lr & 2) ? (p1v[c + 2] + tB) : (p1v[c] + tA);
                float uA = __shfl_xor(p2v[c], 2, 64);
                float uB = __shfl_xor(p2v[c + 2], 2, 64);
                p2v[c] = (lr & 2) ? (p2v[c + 2] + uB) : (p2v[c] + uA);
            }
            {
                float tA = __shfl_xor(p1v[0], 1, 64);
                float tB = __shfl_xor(p1v[1], 1, 64);
                float f1fin = (lr & 1) ? (p1v[1] + tB) : (p1v[0] + tA);
                float uA = __shfl_xor(p2v[0], 1, 64);
                float uB = __shfl_xor(p2v[1], 1, 64);
                float f2fin = (lr & 1) ? (p2v[1] + uB) : (p2v[0] + uA);
                int node = (lr >> 2) * 16 + lq * 4 + (lr & 3);
                F1[w64 + node] = f1fin;
                F2[w64 + node] = f2fin;
            }
        }

        // ---- stats (wave-local): factorized, overwrite F1<-BN, LS<-DN ----
        float pm;
        {
            float p1 = F1[w64 + lane];
            float p2 = F2[w64 + lane];
            float t = (lane < N_) ? p2 : -3.0e38f;
#pragma unroll
            for (int off = 32; off; off >>= 1) t = fmaxf(t, __shfl_xor(t, off, 64));
            pm = t;
            float mprime = pm + p1;
            float m = fmaxf(mprime, 0.2f * mprime);
            float A  = EXP2F(p2 - pm);            // <=1
            float C  = EXP2F(0.2f * (p2 - pm));   // <=1
            float be = EXP2F(mprime - m);
            float de = EXP2F(0.2f * mprime - m);
            float s0 = 0.f, s1 = 0.f;
#pragma unroll
            for (int i = 0; i < N_; i += 2) {
                float aA = rdlane(A, i), aC = rdlane(C, i);
                float bA = rdlane(A, i + 1), bC = rdlane(C, i + 1);
                float ea = fmaxf(aA * be, aC * de);
                float eb = fmaxf(bA * be, bC * de);
                uint32_t w = (i < 32) ? cml : cmh;
                s0 += ((w >> (i & 31)) & 1u) ? ea : 0.f;
                s1 += ((w >> ((i + 1) & 31)) & 1u) ? eb : 0.f;
            }
            float ssum = fmaxf(s0 + s1, 1e-35f);
            float ls = m + LOG2F(ssum);
            F1[w64 + lane] = EXP2F(mprime - ls);          // BN_j <= 1
            LS[w64 + lane] = EXP2F(0.2f * mprime - ls);   // DN_j <= 1
        }

        __syncthreads();   // (A) all hin reads done -> regions become wave-private

        // transpose-store h -> own region as hT[d_local][j] (stride 72);
        // acc fully dead after this.
#pragma unroll
        for (int mt = 0; mt < 4; mt++)
#pragma unroll
            for (int nt = 0; nt < 4; nt++)
                *(bf16x4*)&buf[wreg + (nt * 16 + lr) * S_R + mt * 16 + lq * 4] =
                    pack4(acc[mt][nt]);

        // ---- PV: C[d][i] = sum_j hT[d][j] * P[i][j];
        //      P = mask * max(A_i*BN_j, C_i*DN_j)  (no exp2 in the loop)
        f32x4 acc2[4][4];
#pragma unroll
        for (int mt = 0; mt < 4; mt++)
#pragma unroll
            for (int it = 0; it < 4; it++) acc2[mt][it] = (f32x4){0.f, 0.f, 0.f, 0.f};
        float A4[4], C4[4];
#pragma unroll
        for (int it = 0; it < 4; it++) {
            float f2 = F2[w64 + it * 16 + lr];
            A4[it] = EXP2F(f2 - pm);
            C4[it] = EXP2F(0.2f * (f2 - pm));
        }
#pragma unroll
        for (int kt = 0; kt < 2; kt++) {
            int j0 = kt * 32 + lq * 8;
            bf16x8 pf[4];
#pragma unroll
            for (int h = 0; h < 2; h++) {
                f32x4 bn = *(const f32x4*)&F1[w64 + j0 + 4 * h];
                f32x4 dn = *(const f32x4*)&LS[w64 + j0 + 4 * h];
#pragma unroll
                for (int it = 0; it < 4; it++) {
                    uint64_t mi = msk[it * 16 + lr];
                    uint32_t sh = ((uint32_t)(mi >> (kt * 32))) >> (lq * 8 + 4 * h);
#pragma unroll
                    for (int t = 0; t < 4; t++) {
                        float p = fmaxf(A4[it] * bn[t], C4[it] * dn[t]);
                        p = ((sh >> t) & 1u) ? p : 0.f;
                        pf[it][4 * h + t] = (__bf16)p;
                    }
                }
            }
#pragma unroll
            for (int mt = 0; mt < 4; mt++) {
                bf16x8 ha = *(const bf16x8*)&buf[wreg + (mt * 16 + lr) * S_R + kt * 32 + lq * 8];
#pragma unroll
                for (int it = 0; it < 4; it++)
                    acc2[mt][it] = __builtin_amdgcn_mfma_f32_16x16x32_bf16(
                        ha, pf[it], acc2[mt][it], 0, 0, 0);
            }
        }

        // ---- ELU epilogue -> own region as hout block (node-major); own-
        //      region hT dead (wave-local order), no barrier needed.
#pragma unroll
        for (int mt = 0; mt < 4; mt++)
#pragma unroll
            for (int it = 0; it < 4; it++) {
                int i = it * 16 + lr;
                f32x4 e;
#pragma unroll
                for (int r = 0; r < 4; r++) {
                    float v = acc2[mt][it][r];
                    e[r] = v > 0.f ? v : EXP2F(v * LOG2E) - 1.f;
                }
                *(bf16x4*)&buf[wreg + i * S_R + mt * 16 + lq * 4] = pack4(e);
            }
        // zero pad rows 62,63 of own region (after, same-wave order)
        if (lane < 16) {
            uint4 z = {0u, 0u, 0u, 0u};
            *(uint4*)&buf[wreg + (N_ + (lane >> 3)) * S_R + (lane & 7) * 8] = z;
        }
        __syncthreads();   // (C) hout complete, regions shared again
    }

    // ---- pool + logits + log_softmax ----
    {
        float s = 0.f;
#pragma unroll 2
        for (int n = 0; n < N_; n++)
            s += bf2f(buf[(tid >> 6) * RSZ + n * S_R + (tid & 63)]);
        fstat[tid] = s;
    }
    __syncthreads();
    if (tid < 192) {
        int c = tid >> 6, ln = tid & 63;
        float p = 0.f;
#pragma unroll
        for (int k = ln; k < HID_; k += 64) p += fstat[k] * Wout[k * 3 + c];
        for (int off = 32; off > 0; off >>= 1) p += __shfl_down(p, off, 64);
        if (ln == 0) fstat[1536 + c] = p + bout[c];
    }
    __syncthreads();
    if (tid == 0) {
        float l0 = fstat[1536], l1 = fstat[1537], l2 = fstat[1538];
        float mm = fmaxf(l0, fmaxf(l1, l2));
        float s = __expf(l0 - mm) + __expf(l1 - mm) + __expf(l2 - mm);
        float ls = mm + logf(s);
        out[b * 3 + 0] = l0 - ls;
        out[b * 3 + 1] = l1 - ls;
        out[b * 3 + 2] = l2 - ls;
    }
}

// ---------------------------------------------------------------------------
extern "C" void kernel_launch(void* const* d_in, const int* in_sizes, int n_in,
                              void* d_out, int out_size, void* d_ws, size_t ws_size,
                              hipStream_t stream)
{
    const float* x   = (const float*)d_in[0];
    const int*   adj = (const int*)d_in[1];
    const float* bng = (const float*)d_in[2];
    const float* bnb = (const float*)d_in[3];
    const float* bnm = (const float*)d_in[4];
    const float* bnv = (const float*)d_in[5];
    const float* Wm  = (const float*)d_in[6];
    const float* bm  = (const float*)d_in[7];
    const float* Wg  = (const float*)d_in[8];
    const float* ag  = (const float*)d_in[9];
    const float* Wo  = (const float*)d_in[10];
    const float* bo  = (const float*)d_in[11];
    float* out = (float*)d_out;

    // ws layout: masks | masksT | wmlp_t | wgat2   (~3.8 MB)
    uint64_t* masks  = (uint64_t*)d_ws;
    uint64_t* masksT = masks + (size_t)B_ * 64;
    u16* wmlp_t = (u16*)(masksT + (size_t)B_ * 64);
    u16* wgat2  = wmlp_t + (size_t)HID_ * FIN_;

    int rep_total = HID_ * FIN_ + LAYERS_ * HEADS_ * 64 * HID_;  // 851968
    repack_w<<<(rep_total + 255) / 256, 256, 0, stream>>>(Wm, Wg, wmlp_t, wgat2);
    build_masks<<<B_, 256, 0, stream>>>(adj, masks, masksT);

    gat_fused<<<B_, 512, 0, stream>>>(
        x, bng, bnb, bnm, bnv, wmlp_t, bm, wgat2, ag,
        masks, masksT, Wo, bo, out);
}

// Round 9
// 628.786 us; speedup vs baseline: 1.0719x; 1.0719x over previous
//
#include <hip/hip_runtime.h>
#include <cstdint>
#include <cstddef>

#define B_ 2048
#define N_ 62
#define FIN_ 128
#define HID_ 512
#define HEADS_ 8
#define FOUT_ 64
#define LAYERS_ 3
#define M_ (B_*N_)

typedef __bf16 bf16x8 __attribute__((ext_vector_type(8)));
typedef __bf16 bf16x4 __attribute__((ext_vector_type(4)));
typedef float  f32x4  __attribute__((ext_vector_type(4)));
typedef unsigned short u16;

#define LOG2E 1.4426950408889634f

#if __has_builtin(__builtin_amdgcn_exp2f)
#define EXP2F(x) __builtin_amdgcn_exp2f(x)
#else
#define EXP2F(x) exp2f(x)
#endif
#if __has_builtin(__builtin_amdgcn_logf)
#define LOG2F(x) __builtin_amdgcn_logf(x)
#else
#define LOG2F(x) log2f(x)
#endif

static __device__ __forceinline__ u16 f2bf(float f) {
    union { float f; uint32_t u; } v; v.f = f;
    uint32_t u = v.u;
    return (u16)((u + 0x7fffu + ((u >> 16) & 1u)) >> 16);
}
static __device__ __forceinline__ float bf2f(u16 s) {
    union { uint32_t u; float f; } v; v.u = ((uint32_t)s) << 16;
    return v.f;
}
static __device__ __forceinline__ float rdlane(float v, int l) {
    union { float f; int i; } a, b; a.f = v;
    b.i = __builtin_amdgcn_readlane(a.i, l);
    return b.f;
}
// compiler-friendly pack: emits v_cvt_pk_bf16_f32 pairs (RNE)
static __device__ __forceinline__ bf16x4 pack4(f32x4 v) {
    bf16x4 o;
    o[0] = (__bf16)v[0]; o[1] = (__bf16)v[1];
    o[2] = (__bf16)v[2]; o[3] = (__bf16)v[3];
    return o;
}

// ---------------------------------------------------------------------------
// Pack weights:
//  wmlp_t[n][k]  (n = feature 0..511, k = 0..127), bf16
//  wgat2[l][h][64][512]: row d = W_head^T (col k).
// ---------------------------------------------------------------------------
__global__ __launch_bounds__(256) void repack_w(
    const float* __restrict__ Wm, const float* __restrict__ Wg,
    u16* __restrict__ wmlp_t, u16* __restrict__ wgat2)
{
    int idx = blockIdx.x * 256 + threadIdx.x;
    const int T1 = HID_ * FIN_;                    // 65536
    const int T2 = LAYERS_ * HEADS_ * 64 * HID_;   // 786432
    if (idx < T1) {
        int n = idx / FIN_, k = idx % FIN_;
        wmlp_t[idx] = f2bf(Wm[k * HID_ + n]);
    } else if (idx < T1 + T2) {
        int j = idx - T1;
        int lh = j / (64 * HID_);
        int r  = j % (64 * HID_);
        int n = r / HID_, k = r % HID_;
        wgat2[j] = f2bf(Wg[((size_t)lh * HID_ + k) * FOUT_ + n]);
    }
}

// ---------------------------------------------------------------------------
// adjacency -> per-row 64-bit masks + transposed (per-column) masks
// ---------------------------------------------------------------------------
__global__ __launch_bounds__(256) void build_masks(
    const int* __restrict__ adj, uint64_t* __restrict__ masks,
    uint64_t* __restrict__ masksT)
{
    __shared__ uint32_t m32[128];
    const int b = blockIdx.x, tid = threadIdx.x;
    if (tid < 128) m32[tid] = 0;
    __syncthreads();
    const int* a = adj + (size_t)b * N_ * N_;
    for (int idx = tid; idx < N_ * N_; idx += 256) {
        int i = idx / N_, j = idx % N_;
        if (a[idx] > 0) atomicOr(&m32[i * 2 + (j >> 5)], 1u << (j & 31));
    }
    __syncthreads();
    if (tid < 128) ((uint32_t*)(masks + (size_t)b * 64))[tid] = m32[tid];
    if (tid < 64) {
        int j = tid;
        uint64_t c = 0;
        for (int i = 0; i < N_; i++) {
            uint64_t bit = (m32[i * 2 + (j >> 5)] >> (j & 31)) & 1u;
            c |= bit << i;
        }
        masksT[(size_t)b * 64 + j] = c;
    }
}

// ---------------------------------------------------------------------------
// Fully fused network, one block per graph, wave = head.
// Register budget: __launch_bounds__(512,4) => 128 unified/wave (64 AGPR acc
// pins arch side to 64). NO weight prefetch (r8 post-mortem: any multi-kt
// load window spills). Softmax factorized (exact, proven r8):
//   exp2(leaky(f2_i+f1_j) - LS_j) = max(A_i*BN_j, C_i*DN_j)
// with stats in the lowest-pressure phase (post-bar(A), acc dead).
// Phase order: proj (unroll 1) -> f1/f2 butterfly -> bar(A) -> hT store
//   (acc dies) -> stats (BN/DN) -> PV -> ELU -> bar(C)
// ---------------------------------------------------------------------------
#define S_R  72      // u16 stride inside a region
#define RSZ  4608    // u16 size of a region (64*72)
#define S_X  136     // u16 stride for x-stage [64][S_X]
#define X0   27648   // u16 offset of x-stage (regions 6,7)

__global__ __launch_bounds__(512, 4) void gat_fused(
    const float* __restrict__ x,
    const float* __restrict__ bng, const float* __restrict__ bnb,
    const float* __restrict__ bnm, const float* __restrict__ bnv,
    const u16* __restrict__ wmlp_t, const float* __restrict__ bm,
    const u16* __restrict__ wgat2, const float* __restrict__ ag,
    const uint64_t* __restrict__ masks, const uint64_t* __restrict__ masksT,
    const float* __restrict__ Wout, const float* __restrict__ bout,
    float* __restrict__ out)
{
    __shared__ __align__(16) u16 buf[36864];
    __shared__ uint64_t msk[64];
    __shared__ __align__(16) float fstat[1544];
    float* F1 = fstat;          // [8][64] f1 raw, then BN after stats
    float* F2 = fstat + 512;    // [8][64] f2 (raw, kept)
    float* LS = fstat + 1024;   // [8][64] DN after stats

    const int tid = threadIdx.x, b = blockIdx.x;
    const int wave = tid >> 6, lane = tid & 63;
    const int lr = lane & 15, lq = lane >> 4;
    const int w64 = wave * 64;
    const int wreg = wave * RSZ;

    // per-lane transposed column mask (bit i = adj[i][lane])
    const uint64_t cm = masksT[(size_t)b * 64 + lane];
    const uint32_t cml = (uint32_t)cm, cmh = (uint32_t)(cm >> 32);

    // ---- stage BN(x) -> xs bf16 [64][136] (rows 62,63 zero); stage msk ----
    {
        const float* xg = x + (size_t)b * N_ * FIN_;
        for (int idx = tid; idx < 2048; idx += 512) {
            int n = idx >> 5, kq = idx & 31;
            bf16x4 o = {(__bf16)0.f, (__bf16)0.f, (__bf16)0.f, (__bf16)0.f};
            if (n < N_) {
                float s = bng[n] * rsqrtf(bnv[n] + 1e-5f);
                float sh = bnb[n] - bnm[n] * s;
                float4 v = *(const float4*)(xg + n * FIN_ + kq * 4);
                o[0] = (__bf16)(v.x * s + sh); o[1] = (__bf16)(v.y * s + sh);
                o[2] = (__bf16)(v.z * s + sh); o[3] = (__bf16)(v.w * s + sh);
            }
            *(bf16x4*)&buf[X0 + n * S_X + kq * 4] = o;
        }
        if (tid < 64) msk[tid] = (tid < N_) ? masks[(size_t)b * 64 + tid] : 0ull;
    }
    __syncthreads();

    // ---- MLP (operand-swapped): C[feature][node]; feature block w -> region w
    {
        f32x4 acc[4][4];
#pragma unroll
        for (int mt = 0; mt < 4; mt++)
#pragma unroll
            for (int nt = 0; nt < 4; nt++) acc[mt][nt] = (f32x4){0.f, 0.f, 0.f, 0.f};
        const int c0 = w64;
#pragma unroll 1
        for (int kt = 0; kt < 4; kt++) {
            int k0 = kt * 32;
            bf16x8 xf[4];
#pragma unroll
            for (int nt = 0; nt < 4; nt++)
                xf[nt] = *(const bf16x8*)&buf[X0 + (nt * 16 + lr) * S_X + k0 + lq * 8];
#pragma unroll
            for (int mt = 0; mt < 4; mt++) {
                bf16x8 wf = *(const bf16x8*)(wmlp_t + (size_t)(c0 + mt * 16 + lr) * FIN_ + k0 + lq * 8);
#pragma unroll
                for (int nt = 0; nt < 4; nt++)
                    acc[mt][nt] = __builtin_amdgcn_mfma_f32_16x16x32_bf16(
                        wf, xf[nt], acc[mt][nt], 0, 0, 0);
            }
        }
        __syncthreads();   // xs reads done before region writes (waves 6,7 alias xs)
        f32x4 bl[4];
#pragma unroll
        for (int mt = 0; mt < 4; mt++)
            bl[mt] = *(const f32x4*)&bm[c0 + mt * 16 + lq * 4];
#pragma unroll
        for (int mt = 0; mt < 4; mt++)
#pragma unroll
            for (int nt = 0; nt < 4; nt++) {
                int node = nt * 16 + lr;
                *(bf16x4*)&buf[wreg + node * S_R + mt * 16 + lq * 4] =
                    pack4(acc[mt][nt] + bl[mt]);
            }
        // zero pad rows 62,63 of own region (same-wave order => safe)
        if (lane < 16) {
            uint4 z = {0u, 0u, 0u, 0u};
            *(uint4*)&buf[wreg + (N_ + (lane >> 3)) * S_R + (lane & 7) * 8] = z;
        }
    }
    __syncthreads();

    // ---- GAT layers ----
#pragma unroll 1
    for (int l = 0; l < LAYERS_; l++) {
        const u16* wp = wgat2 + (size_t)(l * HEADS_ + wave) * 64 * HID_;

        // ---- main projection: h = hin @ W_head (64x512 @ 512x64) ----
        // acc[mt][nt][r] = h[node = mt*16+lq*4+r][d = nt*16+lr]
        f32x4 acc[4][4];
#pragma unroll
        for (int mt = 0; mt < 4; mt++)
#pragma unroll
            for (int nt = 0; nt < 4; nt++) acc[mt][nt] = (f32x4){0.f, 0.f, 0.f, 0.f};
#pragma unroll 1
        for (int kt = 0; kt < 16; kt++) {
            int koff = (kt >> 1) * RSZ + (kt & 1) * 32 + lq * 8;
            bf16x8 af[4];
#pragma unroll
            for (int mt = 0; mt < 4; mt++)
                af[mt] = *(const bf16x8*)&buf[koff + (mt * 16 + lr) * S_R];
#pragma unroll
            for (int nt = 0; nt < 4; nt++) {
                bf16x8 bfr = *(const bf16x8*)(wp + (size_t)(nt * 16 + lr) * HID_ + kt * 32 + lq * 8);
#pragma unroll
                for (int mt = 0; mt < 4; mt++)
                    acc[mt][nt] = __builtin_amdgcn_mfma_f32_16x16x32_bf16(
                        af[mt], bfr, acc[mt][nt], 0, 0, 0);
            }
        }

        // ---- f1/f2 in-register from acc (lr-group butterfly) ----
        {
            float a1v[4], a2v[4];
            const float* agl = ag + (size_t)(l * HEADS_ + wave) * 128;
#pragma unroll
            for (int nt = 0; nt < 4; nt++) {
                a1v[nt] = agl[nt * 16 + lr] * LOG2E;
                a2v[nt] = agl[64 + nt * 16 + lr] * LOG2E;
            }
            float p1v[16], p2v[16];
#pragma unroll
            for (int mt = 0; mt < 4; mt++)
#pragma unroll
                for (int r = 0; r < 4; r++) {
                    float s1 = 0.f, s2 = 0.f;
#pragma unroll
                    for (int nt = 0; nt < 4; nt++) {
                        float hv = acc[mt][nt][r];
                        s1 = fmaf(hv, a1v[nt], s1);
                        s2 = fmaf(hv, a2v[nt], s2);
                    }
                    p1v[mt * 4 + r] = s1;
                    p2v[mt * 4 + r] = s2;
                }
#pragma unroll
            for (int c = 0; c < 8; c++) {
                float tA = __shfl_xor(p1v[c], 8, 64);
                float tB = __shfl_xor(p1v[c + 8], 8, 64);
                p1v[c] = (lr & 8) ? (p1v[c + 8] + tB) : (p1v[c] + tA);
                float uA = __shfl_xor(p2v[c], 8, 64);
                float uB = __shfl_xor(p2v[c + 8], 8, 64);
                p2v[c] = (lr & 8) ? (p2v[c + 8] + uB) : (p2v[c] + uA);
            }
#pragma unroll
            for (int c = 0; c < 4; c++) {
                float tA = __shfl_xor(p1v[c], 4, 64);
                float tB = __shfl_xor(p1v[c + 4], 4, 64);
                p1v[c] = (lr & 4) ? (p1v[c + 4] + tB) : (p1v[c] + tA);
                float uA = __shfl_xor(p2v[c], 4, 64);
                float uB = __shfl_xor(p2v[c + 4], 4, 64);
                p2v[c] = (lr & 4) ? (p2v[c + 4] + uB) : (p2v[c] + uA);
            }
#pragma unroll
            for (int c = 0; c < 2; c++) {
                float tA = __shfl_xor(p1v[c], 2, 64);
                float tB = __shfl_xor(p1v[c + 2], 2, 64);
                p1v[c] = (lr & 2) ? (p1v[c + 2] + tB) : (p1v[c] + tA);
                float uA = __shfl_xor(p2v[c], 2, 64);
                float uB = __shfl_xor(p2v[c + 2], 2, 64);
                p2v[c] = (lr & 2) ? (p2v[c + 2] + uB) : (p2v[c] + uA);
            }
            {
                float tA = __shfl_xor(p1v[0], 1, 64);
                float tB = __shfl_xor(p1v[1], 1, 64);
                float f1fin = (lr & 1) ? (p1v[1] + tB) : (p1v[0] + tA);
                float uA = __shfl_xor(p2v[0], 1, 64);
                float uB = __shfl_xor(p2v[1], 1, 64);
                float f2fin = (lr & 1) ? (p2v[1] + uB) : (p2v[0] + uA);
                int node = (lr >> 2) * 16 + lq * 4 + (lr & 3);
                F1[w64 + node] = f1fin;
                F2[w64 + node] = f2fin;
            }
        }

        __syncthreads();   // (A) all hin reads done -> regions become wave-private

        // transpose-store h -> own region as hT[d_local][j] (stride 72);
        // acc fully dead after this -> low pressure for stats.
#pragma unroll
        for (int mt = 0; mt < 4; mt++)
#pragma unroll
            for (int nt = 0; nt < 4; nt++)
                *(bf16x4*)&buf[wreg + (nt * 16 + lr) * S_R + mt * 16 + lq * 4] =
                    pack4(acc[mt][nt]);

        // ---- stats (wave-local, factorized): F1 <- BN, LS <- DN ----
        float pm;
        {
            float p1 = F1[w64 + lane];
            float p2 = F2[w64 + lane];
            float t = (lane < N_) ? p2 : -3.0e38f;
#pragma unroll
            for (int off = 32; off; off >>= 1) t = fmaxf(t, __shfl_xor(t, off, 64));
            pm = t;
            float mprime = pm + p1;
            float m = fmaxf(mprime, 0.2f * mprime);   // >= all masked e in col
            float A  = EXP2F(p2 - pm);            // <=1
            float C  = EXP2F(0.2f * (p2 - pm));   // <=1
            float be = EXP2F(mprime - m);
            float de = EXP2F(0.2f * mprime - m);
            float s0 = 0.f, s1 = 0.f;
#pragma unroll
            for (int i = 0; i < N_; i += 2) {
                float aA = rdlane(A, i), aC = rdlane(C, i);
                float bA = rdlane(A, i + 1), bC = rdlane(C, i + 1);
                float ea = fmaxf(aA * be, aC * de);
                float eb = fmaxf(bA * be, bC * de);
                uint32_t w = (i < 32) ? cml : cmh;
                s0 += ((w >> (i & 31)) & 1u) ? ea : 0.f;
                s1 += ((w >> ((i + 1) & 31)) & 1u) ? eb : 0.f;
            }
            float ssum = fmaxf(s0 + s1, 1e-35f);
            float ls = m + LOG2F(ssum);
            F1[w64 + lane] = EXP2F(mprime - ls);          // BN_j
            LS[w64 + lane] = EXP2F(0.2f * mprime - ls);   // DN_j
        }

        // ---- PV: C[d][i] = sum_j hT[d][j] * P[i][j];
        //      P = mask * max(A_i*BN_j, C_i*DN_j)  (no exp2 in the loop)
        f32x4 acc2[4][4];
#pragma unroll
        for (int mt = 0; mt < 4; mt++)
#pragma unroll
            for (int it = 0; it < 4; it++) acc2[mt][it] = (f32x4){0.f, 0.f, 0.f, 0.f};
        float A4[4], C4[4];
#pragma unroll
        for (int it = 0; it < 4; it++) {
            float f2 = F2[w64 + it * 16 + lr];
            A4[it] = EXP2F(f2 - pm);
            C4[it] = EXP2F(0.2f * (f2 - pm));
        }
#pragma unroll
        for (int kt = 0; kt < 2; kt++) {
            int j0 = kt * 32 + lq * 8;
            bf16x8 pf[4];
#pragma unroll
            for (int h = 0; h < 2; h++) {
                f32x4 bn = *(const f32x4*)&F1[w64 + j0 + 4 * h];
                f32x4 dn = *(const f32x4*)&LS[w64 + j0 + 4 * h];
#pragma unroll
                for (int it = 0; it < 4; it++) {
                    uint64_t mi = msk[it * 16 + lr];
                    uint32_t sh = ((uint32_t)(mi >> (kt * 32))) >> (lq * 8 + 4 * h);
#pragma unroll
                    for (int t = 0; t < 4; t++) {
                        float p = fmaxf(A4[it] * bn[t], C4[it] * dn[t]);
                        p = ((sh >> t) & 1u) ? p : 0.f;
                        pf[it][4 * h + t] = (__bf16)p;
                    }
                }
            }
#pragma unroll
            for (int mt = 0; mt < 4; mt++) {
                bf16x8 ha = *(const bf16x8*)&buf[wreg + (mt * 16 + lr) * S_R + kt * 32 + lq * 8];
#pragma unroll
                for (int it = 0; it < 4; it++)
                    acc2[mt][it] = __builtin_amdgcn_mfma_f32_16x16x32_bf16(
                        ha, pf[it], acc2[mt][it], 0, 0, 0);
            }
        }

        // ---- ELU epilogue -> own region as hout block (node-major); own-
        //      region hT dead (wave-local order), no barrier needed.
#pragma unroll
        for (int mt = 0; mt < 4; mt++)
#pragma unroll
            for (int it = 0; it < 4; it++) {
                int i = it * 16 + lr;
                f32x4 e;
#pragma unroll
                for (int r = 0; r < 4; r++) {
                    float v = acc2[mt][it][r];
                    e[r] = v > 0.f ? v : EXP2F(v * LOG2E) - 1.f;
                }
                *(bf16x4*)&buf[wreg + i * S_R + mt * 16 + lq * 4] = pack4(e);
            }
        // zero pad rows 62,63 of own region (same-wave order => safe)
        if (lane < 16) {
            uint4 z = {0u, 0u, 0u, 0u};
            *(uint4*)&buf[wreg + (N_ + (lane >> 3)) * S_R + (lane & 7) * 8] = z;
        }
        __syncthreads();   // (C) hout complete, regions shared again
    }

    // ---- pool + logits + log_softmax ----
    {
        float s = 0.f;
#pragma unroll 2
        for (int n = 0; n < N_; n++)
            s += bf2f(buf[(tid >> 6) * RSZ + n * S_R + (tid & 63)]);
        fstat[tid] = s;
    }
    __syncthreads();
    if (tid < 192) {
        int c = tid >> 6, ln = tid & 63;
        float p = 0.f;
#pragma unroll
        for (int k = ln; k < HID_; k += 64) p += fstat[k] * Wout[k * 3 + c];
        for (int off = 32; off > 0; off >>= 1) p += __shfl_down(p, off, 64);
        if (ln == 0) fstat[1536 + c] = p + bout[c];
    }
    __syncthreads();
    if (tid == 0) {
        float l0 = fstat[1536], l1 = fstat[1537], l2 = fstat[1538];
        float mm = fmaxf(l0, fmaxf(l1, l2));
        float s = __expf(l0 - mm) + __expf(l1 - mm) + __expf(l2 - mm);
        float ls = mm + logf(s);
        out[b * 3 + 0] = l0 - ls;
        out[b * 3 + 1] = l1 - ls;
        out[b * 3 + 2] = l2 - ls;
    }
}

// ---------------------------------------------------------------------------
extern "C" void kernel_launch(void* const* d_in, const int* in_sizes, int n_in,
                              void* d_out, int out_size, void* d_ws, size_t ws_size,
                              hipStream_t stream)
{
    const float* x   = (const float*)d_in[0];
    const int*   adj = (const int*)d_in[1];
    const float* bng = (const float*)d_in[2];
    const float* bnb = (const float*)d_in[3];
    const float* bnm = (const float*)d_in[4];
    const float* bnv = (const float*)d_in[5];
    const float* Wm  = (const float*)d_in[6];
    const float* bm  = (const float*)d_in[7];
    const float* Wg  = (const float*)d_in[8];
    const float* ag  = (const float*)d_in[9];
    const float* Wo  = (const float*)d_in[10];
    const float* bo  = (const float*)d_in[11];
    float* out = (float*)d_out;

    // ws layout: masks | masksT | wmlp_t | wgat2   (~3.8 MB)
    uint64_t* masks  = (uint64_t*)d_ws;
    uint64_t* masksT = masks + (size_t)B_ * 64;
    u16* wmlp_t = (u16*)(masksT + (size_t)B_ * 64);
    u16* wgat2  = wmlp_t + (size_t)HID_ * FIN_;

    int rep_total = HID_ * FIN_ + LAYERS_ * HEADS_ * 64 * HID_;  // 851968
    repack_w<<<(rep_total + 255) / 256, 256, 0, stream>>>(Wm, Wg, wmlp_t, wgat2);
    build_masks<<<B_, 256, 0, stream>>>(adj, masks, masksT);

    gat_fused<<<B_, 512, 0, stream>>>(
        x, bng, bnb, bnm, bnv, wmlp_t, bm, wgat2, ag,
        masks, masksT, Wo, bo, out);
}